// Round 1
// baseline (92.451 us; speedup 1.0000x reference)
//
#include <hip/hip_runtime.h>
#include <math.h>

#define NB 64
#define NL 512
#define ND 768

static constexpr float kCosEps = 1e-8f;
static constexpr double kBnEps = 1e-5;

// ---- workspace layout (bytes) ----
static constexpr size_t OFF_ACC = 0;                         // 2 doubles (sum, sumsq)
static constexpr size_t OFF_CSN = 256;                       // [8][NB][ND] f32 partial colsums of news
static constexpr size_t SZ_PART = (size_t)8 * NB * ND * 4;
static constexpr size_t OFF_CSP = OFF_CSN + SZ_PART;         // [8][NB][ND] f32 partial colsums of post
static constexpr size_t OFF_COS = OFF_CSP + SZ_PART;         // [NB][NL] f32 cosine
static constexpr size_t SZ_BL   = (size_t)NB * NL * 4;
static constexpr size_t OFF_HI  = OFF_COS + SZ_BL;           // interior conv rows
static constexpr size_t OFF_HT  = OFF_HI + SZ_BL;            // top row
static constexpr size_t OFF_HB  = OFF_HT + SZ_BL;            // bottom row
static constexpr size_t OFF_ABC = OFF_HB + SZ_BL;            // [NB][3] f32 (a, ct, cb)

// ---------------------------------------------------------------------------
// k1: per-(b,l) cosine similarity + fused per-(b,d) column sums of news/post.
// grid = NB*8 blocks (8 l-tiles of 64 rows per batch), 256 threads = 4 waves.
// Wave w handles rows tile*64 + 4*r + w, r=0..15. Lane loads 3 float4 per row.
// ---------------------------------------------------------------------------
__global__ __launch_bounds__(256) void k1_cos_colsum(
    const float* __restrict__ news, const float* __restrict__ post,
    float* __restrict__ cosv, float* __restrict__ csn_part,
    float* __restrict__ csp_part)
{
    __shared__ float lds_n[4][ND];
    __shared__ float lds_p[4][ND];
    const int b    = blockIdx.x >> 3;
    const int tile = blockIdx.x & 7;
    const int tid  = threadIdx.x;
    const int wave = tid >> 6;
    const int lane = tid & 63;

    float an[12], ap[12];
#pragma unroll
    for (int k = 0; k < 12; ++k) { an[k] = 0.f; ap[k] = 0.f; }

    for (int r = 0; r < 16; ++r) {
        const int l = tile * 64 + r * 4 + wave;
        const float4* nrow = (const float4*)(news + ((size_t)b * NL + l) * ND);
        const float4* prow = (const float4*)(post + ((size_t)b * NL + l) * ND);
        float nn = 0.f, pp = 0.f, npd = 0.f;
#pragma unroll
        for (int k = 0; k < 3; ++k) {
            const float4 nv = nrow[lane + 64 * k];
            const float4 pv = prow[lane + 64 * k];
            nn  += nv.x * nv.x + nv.y * nv.y + nv.z * nv.z + nv.w * nv.w;
            pp  += pv.x * pv.x + pv.y * pv.y + pv.z * pv.z + pv.w * pv.w;
            npd += nv.x * pv.x + nv.y * pv.y + nv.z * pv.z + nv.w * pv.w;
            an[4 * k + 0] += nv.x; an[4 * k + 1] += nv.y;
            an[4 * k + 2] += nv.z; an[4 * k + 3] += nv.w;
            ap[4 * k + 0] += pv.x; ap[4 * k + 1] += pv.y;
            ap[4 * k + 2] += pv.z; ap[4 * k + 3] += pv.w;
        }
#pragma unroll
        for (int m = 32; m >= 1; m >>= 1) {
            nn  += __shfl_xor(nn, m);
            pp  += __shfl_xor(pp, m);
            npd += __shfl_xor(npd, m);
        }
        if (lane == 0) {
            const float dn = fmaxf(sqrtf(nn), kCosEps) * fmaxf(sqrtf(pp), kCosEps);
            cosv[b * NL + l] = npd / dn;
        }
    }
    // per-wave colsum partials -> LDS (exclusive regions, no atomics)
#pragma unroll
    for (int k = 0; k < 3; ++k) {
        const int d0 = 4 * (lane + 64 * k);
        lds_n[wave][d0 + 0] = an[4 * k + 0]; lds_n[wave][d0 + 1] = an[4 * k + 1];
        lds_n[wave][d0 + 2] = an[4 * k + 2]; lds_n[wave][d0 + 3] = an[4 * k + 3];
        lds_p[wave][d0 + 0] = ap[4 * k + 0]; lds_p[wave][d0 + 1] = ap[4 * k + 1];
        lds_p[wave][d0 + 2] = ap[4 * k + 2]; lds_p[wave][d0 + 3] = ap[4 * k + 3];
    }
    __syncthreads();
    float* outn = csn_part + ((size_t)tile * NB + b) * ND;
    float* outp = csp_part + ((size_t)tile * NB + b) * ND;
    for (int i = tid; i < ND; i += 256) {
        outn[i] = lds_n[0][i] + lds_n[1][i] + lds_n[2][i] + lds_n[3][i];
        outp[i] = lds_p[0][i] + lds_p[1][i] + lds_p[2][i] + lds_p[3][i];
    }
}

// ---------------------------------------------------------------------------
// k2: 3-tap horizontal conv of cos row (3 vertical-weight variants) +
// fp64 global sum / sum-of-squares with multiplicities (1, L-2, 1).
// grid = NB blocks, 256 threads.
// ---------------------------------------------------------------------------
__global__ __launch_bounds__(256) void k2_conv_stats(
    const float* __restrict__ cosv, const float* __restrict__ g,
    float* __restrict__ hi, float* __restrict__ ht, float* __restrict__ hb,
    double* __restrict__ acc)
{
    __shared__ float row[NL + 2];
    __shared__ double sred[8];
    const int b   = blockIdx.x;
    const int tid = threadIdx.x;
    if (tid == 0) { row[0] = 0.f; row[NL + 1] = 0.f; }
    for (int j = tid; j < NL; j += 256) row[j + 1] = cosv[b * NL + j];
    __syncthreads();

    // column sums of the 3x3 kernel for interior / top(i=0) / bottom(i=L-1) rows
    const float ci0 = g[0] + g[3] + g[6], ci1 = g[1] + g[4] + g[7], ci2 = g[2] + g[5] + g[8];
    const float ct0 = g[3] + g[6],        ct1 = g[4] + g[7],        ct2 = g[5] + g[8];
    const float cb0 = g[0] + g[3],        cb1 = g[1] + g[4],        cb2 = g[2] + g[5];

    double s = 0.0, s2 = 0.0;
    for (int j = tid; j < NL; j += 256) {
        const float a = row[j], c = row[j + 1], d = row[j + 2];
        const float vi = ci0 * a + ci1 * c + ci2 * d;
        const float vt = ct0 * a + ct1 * c + ct2 * d;
        const float vb = cb0 * a + cb1 * c + cb2 * d;
        hi[b * NL + j] = vi; ht[b * NL + j] = vt; hb[b * NL + j] = vb;
        s  += (double)vi * (NL - 2) + (double)vt + (double)vb;
        s2 += (double)vi * vi * (NL - 2) + (double)vt * vt + (double)vb * vb;
    }
    const int lane = tid & 63, wave = tid >> 6;
#pragma unroll
    for (int m = 32; m >= 1; m >>= 1) { s += __shfl_xor(s, m); s2 += __shfl_xor(s2, m); }
    if (lane == 0) { sred[wave] = s; sred[4 + wave] = s2; }
    __syncthreads();
    if (tid == 0) {
        atomicAdd(&acc[0], sred[0] + sred[1] + sred[2] + sred[3]);
        atomicAdd(&acc[1], sred[4] + sred[5] + sred[6] + sred[7]);
    }
}

// ---------------------------------------------------------------------------
// k3: normalize (global BN), z = h_hat @ W^T + b for the 3 variants,
// collapsed softmax over l (multiplicities 1, L-2, 1), sum over n.
// grid = NB blocks, 256 threads (each thread handles 2 n-rows).
// ---------------------------------------------------------------------------
__global__ __launch_bounds__(256) void k3_linear_softmax(
    const float* __restrict__ hi, const float* __restrict__ ht,
    const float* __restrict__ hb, const float* __restrict__ W,
    const float* __restrict__ bias, const float* __restrict__ gamma,
    const float* __restrict__ beta, const double* __restrict__ acc,
    float* __restrict__ abc)
{
    __shared__ float shi[NL], sht[NL], shb[NL];
    __shared__ float sred[12];
    const int b   = blockIdx.x;
    const int tid = threadIdx.x;

    const double N   = (double)NB * NL * NL;
    const double mu  = acc[0] / N;
    const double var = acc[1] / N - mu * mu;
    const float  sc  = gamma[0] * (float)(1.0 / sqrt(var + kBnEps));
    const float  sh  = beta[0] - (float)mu * sc;

    for (int j = tid; j < NL; j += 256) {
        shi[j] = hi[b * NL + j] * sc + sh;
        sht[j] = ht[b * NL + j] * sc + sh;
        shb[j] = hb[b * NL + j] * sc + sh;
    }
    __syncthreads();

    const float4* s4i = (const float4*)shi;
    const float4* s4t = (const float4*)sht;
    const float4* s4b = (const float4*)shb;

    float sa = 0.f, st = 0.f, sb = 0.f;
    for (int n = tid; n < NL; n += 256) {
        const float4* wr = (const float4*)(W + (size_t)n * NL);
        float zi = 0.f, zt = 0.f, zb = 0.f;
        for (int m = 0; m < NL / 4; ++m) {
            const float4 w  = wr[m];
            const float4 vi = s4i[m], vt = s4t[m], vb = s4b[m];
            zi += w.x * vi.x + w.y * vi.y + w.z * vi.z + w.w * vi.w;
            zt += w.x * vt.x + w.y * vt.y + w.z * vt.z + w.w * vt.w;
            zb += w.x * vb.x + w.y * vb.y + w.z * vb.z + w.w * vb.w;
        }
        const float bv = bias[n];
        zi += bv; zt += bv; zb += bv;
        const float M  = fmaxf(zi, fmaxf(zt, zb));
        const float ei = expf(zi - M), et = expf(zt - M), eb = expf(zb - M);
        const float r  = 1.f / ((float)(NL - 2) * ei + et + eb);
        sa += ei * r; st += et * r; sb += eb * r;
    }
    const int lane = tid & 63, wave = tid >> 6;
#pragma unroll
    for (int m = 32; m >= 1; m >>= 1) {
        sa += __shfl_xor(sa, m); st += __shfl_xor(st, m); sb += __shfl_xor(sb, m);
    }
    if (lane == 0) { sred[wave * 3] = sa; sred[wave * 3 + 1] = st; sred[wave * 3 + 2] = sb; }
    __syncthreads();
    if (tid == 0) {
        abc[b * 3 + 0] = sred[0] + sred[3] + sred[6] + sred[9];
        abc[b * 3 + 1] = sred[1] + sred[4] + sred[7] + sred[10];
        abc[b * 3 + 2] = sred[2] + sred[5] + sred[8] + sred[11];
    }
}

// ---------------------------------------------------------------------------
// k4: outputs. word_feat[b,d] = (a*colsum_n + (ct-a)*news[b,0,d] + (cb-a)*news[b,L-1,d]) / L
// (and same for post). Sums the 8 colsum partials. grid = NB*ND/256 = 192.
// ---------------------------------------------------------------------------
__global__ __launch_bounds__(256) void k4_out(
    const float* __restrict__ news, const float* __restrict__ post,
    const float* __restrict__ csn_part, const float* __restrict__ csp_part,
    const float* __restrict__ abc, float* __restrict__ out)
{
    const int idx = blockIdx.x * 256 + threadIdx.x;
    if (idx >= NB * ND) return;
    const int b = idx / ND, d = idx - b * ND;
    const float a  = abc[b * 3 + 0];
    const float ct = abc[b * 3 + 1];
    const float cb = abc[b * 3 + 2];
    float cn = 0.f, cp = 0.f;
#pragma unroll
    for (int t = 0; t < 8; ++t) {
        cn += csn_part[((size_t)t * NB + b) * ND + d];
        cp += csp_part[((size_t)t * NB + b) * ND + d];
    }
    const size_t base = (size_t)b * NL * ND;
    const float n0 = news[base + d], nL = news[base + (size_t)(NL - 1) * ND + d];
    const float p0 = post[base + d], pL = post[base + (size_t)(NL - 1) * ND + d];
    const float invL = 1.f / NL;
    out[idx]           = (a * cn + (ct - a) * n0 + (cb - a) * nL) * invL;
    out[NB * ND + idx] = (a * cp + (ct - a) * p0 + (cb - a) * pL) * invL;
}

extern "C" void kernel_launch(void* const* d_in, const int* in_sizes, int n_in,
                              void* d_out, int out_size, void* d_ws, size_t ws_size,
                              hipStream_t stream) {
    const float* news     = (const float*)d_in[0];
    const float* post     = (const float*)d_in[1];
    const float* g        = (const float*)d_in[2];
    const float* bn_gamma = (const float*)d_in[3];
    const float* bn_beta  = (const float*)d_in[4];
    const float* lin_w    = (const float*)d_in[5];
    const float* lin_b    = (const float*)d_in[6];
    float* out = (float*)d_out;
    char*  ws  = (char*)d_ws;

    double* acc = (double*)(ws + OFF_ACC);
    float* csn  = (float*)(ws + OFF_CSN);
    float* csp  = (float*)(ws + OFF_CSP);
    float* cosv = (float*)(ws + OFF_COS);
    float* hi   = (float*)(ws + OFF_HI);
    float* ht   = (float*)(ws + OFF_HT);
    float* hb   = (float*)(ws + OFF_HB);
    float* abc  = (float*)(ws + OFF_ABC);

    // zero the fp64 accumulators (ws is poisoned; everything else is
    // fully overwritten every call)
    hipMemsetAsync(acc, 0, 2 * sizeof(double), stream);

    k1_cos_colsum<<<NB * 8, 256, 0, stream>>>(news, post, cosv, csn, csp);
    k2_conv_stats<<<NB, 256, 0, stream>>>(cosv, g, hi, ht, hb, acc);
    k3_linear_softmax<<<NB, 256, 0, stream>>>(hi, ht, hb, lin_w, lin_b,
                                              bn_gamma, bn_beta, acc, abc);
    k4_out<<<192, 256, 0, stream>>>(news, post, csn, csp, abc, out);
}

// Round 2
// 87.736 us; speedup vs baseline: 1.0537x; 1.0537x over previous
//
#include <hip/hip_runtime.h>
#include <math.h>

#define NB 64
#define NL 512
#define ND 768

static constexpr float kCosEps = 1e-8f;
static constexpr double kBnEps = 1e-5;

// ---- workspace layout (bytes) ----
static constexpr size_t OFF_ACC = 0;                         // 2 doubles (sum, sumsq)
static constexpr size_t OFF_CSN = 256;                       // [8][NB][ND] f32 partial colsums of news
static constexpr size_t SZ_PART = (size_t)8 * NB * ND * 4;
static constexpr size_t OFF_CSP = OFF_CSN + SZ_PART;         // [8][NB][ND] f32 partial colsums of post
static constexpr size_t OFF_COS = OFF_CSP + SZ_PART;         // [NB][NL] f32 cosine
static constexpr size_t SZ_BL   = (size_t)NB * NL * 4;
static constexpr size_t OFF_HI  = OFF_COS + SZ_BL;           // interior conv rows
static constexpr size_t OFF_HT  = OFF_HI + SZ_BL;            // top row
static constexpr size_t OFF_HB  = OFF_HT + SZ_BL;            // bottom row
static constexpr size_t OFF_ABC = OFF_HB + SZ_BL;            // [NB][3] f32 (a, ct, cb)

// ---------------------------------------------------------------------------
// k1: per-(b,l) cosine similarity + fused per-(b,d) column sums of news/post.
// grid = NB*8 (one block per batch x 64-row tile), block = 1024 thr = 16 waves
// -> 2 blocks/CU = 32 waves/CU (100% occupancy; round-1 had 8/CU and was
// latency-bound at 20% occupancy / 1.2 TB/s).
// Wave w handles rows tile*64 + r*16 + w, r=0..3. Lane loads 3 float4 per row.
// LDS: one 16x768 buffer (48 KB), reused news-then-post for the colsum reduce.
// ---------------------------------------------------------------------------
__global__ __launch_bounds__(1024) void k1_cos_colsum(
    const float* __restrict__ news, const float* __restrict__ post,
    float* __restrict__ cosv, float* __restrict__ csn_part,
    float* __restrict__ csp_part)
{
    __shared__ float lds[16][ND];   // 48 KB
    const int b    = blockIdx.x >> 3;
    const int tile = blockIdx.x & 7;
    const int tid  = threadIdx.x;
    const int wave = tid >> 6;      // 0..15
    const int lane = tid & 63;

    float an[12], ap[12];
#pragma unroll
    for (int k = 0; k < 12; ++k) { an[k] = 0.f; ap[k] = 0.f; }

#pragma unroll
    for (int r = 0; r < 4; ++r) {
        const int l = tile * 64 + r * 16 + wave;
        const float4* nrow = (const float4*)(news + ((size_t)b * NL + l) * ND);
        const float4* prow = (const float4*)(post + ((size_t)b * NL + l) * ND);
        float nn = 0.f, pp = 0.f, npd = 0.f;
#pragma unroll
        for (int k = 0; k < 3; ++k) {
            const float4 nv = nrow[lane + 64 * k];
            const float4 pv = prow[lane + 64 * k];
            nn  += nv.x * nv.x + nv.y * nv.y + nv.z * nv.z + nv.w * nv.w;
            pp  += pv.x * pv.x + pv.y * pv.y + pv.z * pv.z + pv.w * pv.w;
            npd += nv.x * pv.x + nv.y * pv.y + nv.z * pv.z + nv.w * pv.w;
            an[4 * k + 0] += nv.x; an[4 * k + 1] += nv.y;
            an[4 * k + 2] += nv.z; an[4 * k + 3] += nv.w;
            ap[4 * k + 0] += pv.x; ap[4 * k + 1] += pv.y;
            ap[4 * k + 2] += pv.z; ap[4 * k + 3] += pv.w;
        }
#pragma unroll
        for (int m = 32; m >= 1; m >>= 1) {
            nn  += __shfl_xor(nn, m);
            pp  += __shfl_xor(pp, m);
            npd += __shfl_xor(npd, m);
        }
        if (lane == 0) {
            const float dn = fmaxf(sqrtf(nn), kCosEps) * fmaxf(sqrtf(pp), kCosEps);
            cosv[b * NL + l] = npd / dn;
        }
    }

    // ---- colsum reduce, phase A (news) ----
    float4* ldsrow = (float4*)&lds[wave][0];
#pragma unroll
    for (int k = 0; k < 3; ++k)
        ldsrow[lane + 64 * k] = make_float4(an[4 * k + 0], an[4 * k + 1],
                                            an[4 * k + 2], an[4 * k + 3]);
    __syncthreads();
    if (tid < ND) {
        float s = 0.f;
#pragma unroll
        for (int w = 0; w < 16; ++w) s += lds[w][tid];
        csn_part[((size_t)tile * NB + b) * ND + tid] = s;
    }
    __syncthreads();
    // ---- colsum reduce, phase B (post) ----
#pragma unroll
    for (int k = 0; k < 3; ++k)
        ldsrow[lane + 64 * k] = make_float4(ap[4 * k + 0], ap[4 * k + 1],
                                            ap[4 * k + 2], ap[4 * k + 3]);
    __syncthreads();
    if (tid < ND) {
        float s = 0.f;
#pragma unroll
        for (int w = 0; w < 16; ++w) s += lds[w][tid];
        csp_part[((size_t)tile * NB + b) * ND + tid] = s;
    }
}

// ---------------------------------------------------------------------------
// k2: 3-tap horizontal conv of cos row (3 vertical-weight variants) +
// fp64 global sum / sum-of-squares with multiplicities (1, L-2, 1).
// grid = NB blocks, 256 threads.
// ---------------------------------------------------------------------------
__global__ __launch_bounds__(256) void k2_conv_stats(
    const float* __restrict__ cosv, const float* __restrict__ g,
    float* __restrict__ hi, float* __restrict__ ht, float* __restrict__ hb,
    double* __restrict__ acc)
{
    __shared__ float row[NL + 2];
    __shared__ double sred[8];
    const int b   = blockIdx.x;
    const int tid = threadIdx.x;
    if (tid == 0) { row[0] = 0.f; row[NL + 1] = 0.f; }
    for (int j = tid; j < NL; j += 256) row[j + 1] = cosv[b * NL + j];
    __syncthreads();

    const float ci0 = g[0] + g[3] + g[6], ci1 = g[1] + g[4] + g[7], ci2 = g[2] + g[5] + g[8];
    const float ct0 = g[3] + g[6],        ct1 = g[4] + g[7],        ct2 = g[5] + g[8];
    const float cb0 = g[0] + g[3],        cb1 = g[1] + g[4],        cb2 = g[2] + g[5];

    double s = 0.0, s2 = 0.0;
    for (int j = tid; j < NL; j += 256) {
        const float a = row[j], c = row[j + 1], d = row[j + 2];
        const float vi = ci0 * a + ci1 * c + ci2 * d;
        const float vt = ct0 * a + ct1 * c + ct2 * d;
        const float vb = cb0 * a + cb1 * c + cb2 * d;
        hi[b * NL + j] = vi; ht[b * NL + j] = vt; hb[b * NL + j] = vb;
        s  += (double)vi * (NL - 2) + (double)vt + (double)vb;
        s2 += (double)vi * vi * (NL - 2) + (double)vt * vt + (double)vb * vb;
    }
    const int lane = tid & 63, wave = tid >> 6;
#pragma unroll
    for (int m = 32; m >= 1; m >>= 1) { s += __shfl_xor(s, m); s2 += __shfl_xor(s2, m); }
    if (lane == 0) { sred[wave] = s; sred[4 + wave] = s2; }
    __syncthreads();
    if (tid == 0) {
        atomicAdd(&acc[0], sred[0] + sred[1] + sred[2] + sred[3]);
        atomicAdd(&acc[1], sred[4] + sred[5] + sred[6] + sred[7]);
    }
}

// ---------------------------------------------------------------------------
// k3: normalize (global BN), z = h_hat @ W^T + b for the 3 variants,
// collapsed softmax over l (multiplicities 1, L-2, 1), sum over n.
// grid = NB blocks, 256 threads.
// ---------------------------------------------------------------------------
__global__ __launch_bounds__(256) void k3_linear_softmax(
    const float* __restrict__ hi, const float* __restrict__ ht,
    const float* __restrict__ hb, const float* __restrict__ W,
    const float* __restrict__ bias, const float* __restrict__ gamma,
    const float* __restrict__ beta, const double* __restrict__ acc,
    float* __restrict__ abc)
{
    __shared__ float shi[NL], sht[NL], shb[NL];
    __shared__ float sred[12];
    const int b   = blockIdx.x;
    const int tid = threadIdx.x;

    const double N   = (double)NB * NL * NL;
    const double mu  = acc[0] / N;
    const double var = acc[1] / N - mu * mu;
    const float  sc  = gamma[0] * (float)(1.0 / sqrt(var + kBnEps));
    const float  sh  = beta[0] - (float)mu * sc;

    for (int j = tid; j < NL; j += 256) {
        shi[j] = hi[b * NL + j] * sc + sh;
        sht[j] = ht[b * NL + j] * sc + sh;
        shb[j] = hb[b * NL + j] * sc + sh;
    }
    __syncthreads();

    const float4* s4i = (const float4*)shi;
    const float4* s4t = (const float4*)sht;
    const float4* s4b = (const float4*)shb;

    float sa = 0.f, st = 0.f, sb = 0.f;
    for (int n = tid; n < NL; n += 256) {
        const float4* wr = (const float4*)(W + (size_t)n * NL);
        float zi = 0.f, zt = 0.f, zb = 0.f;
        for (int m = 0; m < NL / 4; ++m) {
            const float4 w  = wr[m];
            const float4 vi = s4i[m], vt = s4t[m], vb = s4b[m];
            zi += w.x * vi.x + w.y * vi.y + w.z * vi.z + w.w * vi.w;
            zt += w.x * vt.x + w.y * vt.y + w.z * vt.z + w.w * vt.w;
            zb += w.x * vb.x + w.y * vb.y + w.z * vb.z + w.w * vb.w;
        }
        const float bv = bias[n];
        zi += bv; zt += bv; zb += bv;
        const float M  = fmaxf(zi, fmaxf(zt, zb));
        const float ei = expf(zi - M), et = expf(zt - M), eb = expf(zb - M);
        const float r  = 1.f / ((float)(NL - 2) * ei + et + eb);
        sa += ei * r; st += et * r; sb += eb * r;
    }
    const int lane = tid & 63, wave = tid >> 6;
#pragma unroll
    for (int m = 32; m >= 1; m >>= 1) {
        sa += __shfl_xor(sa, m); st += __shfl_xor(st, m); sb += __shfl_xor(sb, m);
    }
    if (lane == 0) { sred[wave * 3] = sa; sred[wave * 3 + 1] = st; sred[wave * 3 + 2] = sb; }
    __syncthreads();
    if (tid == 0) {
        abc[b * 3 + 0] = sred[0] + sred[3] + sred[6] + sred[9];
        abc[b * 3 + 1] = sred[1] + sred[4] + sred[7] + sred[10];
        abc[b * 3 + 2] = sred[2] + sred[5] + sred[8] + sred[11];
    }
}

// ---------------------------------------------------------------------------
// k4: outputs. word_feat[b,d] = (a*colsum_n + (ct-a)*n0 + (cb-a)*nL)/L, same
// for post. Sums the 8 colsum partials. grid = NB*ND/256 = 192.
// ---------------------------------------------------------------------------
__global__ __launch_bounds__(256) void k4_out(
    const float* __restrict__ news, const float* __restrict__ post,
    const float* __restrict__ csn_part, const float* __restrict__ csp_part,
    const float* __restrict__ abc, float* __restrict__ out)
{
    const int idx = blockIdx.x * 256 + threadIdx.x;
    if (idx >= NB * ND) return;
    const int b = idx / ND, d = idx - b * ND;
    const float a  = abc[b * 3 + 0];
    const float ct = abc[b * 3 + 1];
    const float cb = abc[b * 3 + 2];
    float cn = 0.f, cp = 0.f;
#pragma unroll
    for (int t = 0; t < 8; ++t) {
        cn += csn_part[((size_t)t * NB + b) * ND + d];
        cp += csp_part[((size_t)t * NB + b) * ND + d];
    }
    const size_t base = (size_t)b * NL * ND;
    const float n0 = news[base + d], nL = news[base + (size_t)(NL - 1) * ND + d];
    const float p0 = post[base + d], pL = post[base + (size_t)(NL - 1) * ND + d];
    const float invL = 1.f / NL;
    out[idx]           = (a * cn + (ct - a) * n0 + (cb - a) * nL) * invL;
    out[NB * ND + idx] = (a * cp + (ct - a) * p0 + (cb - a) * pL) * invL;
}

extern "C" void kernel_launch(void* const* d_in, const int* in_sizes, int n_in,
                              void* d_out, int out_size, void* d_ws, size_t ws_size,
                              hipStream_t stream) {
    const float* news     = (const float*)d_in[0];
    const float* post     = (const float*)d_in[1];
    const float* g        = (const float*)d_in[2];
    const float* bn_gamma = (const float*)d_in[3];
    const float* bn_beta  = (const float*)d_in[4];
    const float* lin_w    = (const float*)d_in[5];
    const float* lin_b    = (const float*)d_in[6];
    float* out = (float*)d_out;
    char*  ws  = (char*)d_ws;

    double* acc = (double*)(ws + OFF_ACC);
    float* csn  = (float*)(ws + OFF_CSN);
    float* csp  = (float*)(ws + OFF_CSP);
    float* cosv = (float*)(ws + OFF_COS);
    float* hi   = (float*)(ws + OFF_HI);
    float* ht   = (float*)(ws + OFF_HT);
    float* hb   = (float*)(ws + OFF_HB);
    float* abc  = (float*)(ws + OFF_ABC);

    hipMemsetAsync(acc, 0, 2 * sizeof(double), stream);

    k1_cos_colsum<<<NB * 8, 1024, 0, stream>>>(news, post, cosv, csn, csp);
    k2_conv_stats<<<NB, 256, 0, stream>>>(cosv, g, hi, ht, hb, acc);
    k3_linear_softmax<<<NB, 256, 0, stream>>>(hi, ht, hb, lin_w, lin_b,
                                              bn_gamma, bn_beta, acc, abc);
    k4_out<<<192, 256, 0, stream>>>(news, post, csn, csp, abc, out);
}